// Round 7
// baseline (578.279 us; speedup 1.0000x reference)
//
#include <hip/hip_runtime.h>
#include <hip/hip_cooperative_groups.h>
#include <hip/hip_bf16.h>
#include <math.h>

namespace cg = cooperative_groups;

// Problem constants (B=1)
constexpr int S  = 2048;
constexpr int D  = 1024;
constexpr int H  = 16;
constexpr int HD = 64;
constexpr int FF = 4096;
constexpr int NC  = 32;   // chunks for linear attention
constexpr int CHK = 64;   // chunk length
constexpr int QS  = 3 * D;

constexpr int NBLK = 256;   // 144KB LDS -> 1 block/CU; cooperative launch VERIFIES residency
constexpr int NTHR = 512;

typedef __attribute__((ext_vector_type(8))) short bf16x8;
typedef __attribute__((ext_vector_type(16))) float f32x16;

__device__ inline unsigned short f2bf(float f) {
    unsigned int u = __float_as_uint(f);
    u = (u + 0x7FFFu + ((u >> 16) & 1u)) >> 16;   // RNE
    return (unsigned short)u;
}

constexpr int DD4 = D * D / 4;
constexpr int FD4 = FF * D / 4;
constexpr int CVT_TOTAL4 = 4 * DD4 + 2 * FD4;   // 3145728

enum { EPI_QKV = 1, EPI_GELU_BF16 = 2, EPI_PART = 3 };

// ---- 256x128-tile bf16 GEMM phase (512 thr, 8 waves 4Mx2N, 32x32x16 MFMA).
// Depth-3 LDS pipeline, counted vmcnt(6) (T3+T4), raw s_barrier, XOR-swizzled
// LDS via pre-swizzled GLOBAL source (verified SQ_LDS_BANK_CONFLICT==0, R3-R5).
template <int EPI>
__device__ void gemm_phase(const unsigned short* __restrict__ A,
                           const unsigned short* __restrict__ W,
                           const float* __restrict__ bias,
                           const float* __restrict__ bias2,
                           const float* __restrict__ bias3,
                           void* __restrict__ outp,
                           int M, int N, int K,
                           int tileM, int tileN, int kStart, int kLen, int zIdx,
                           unsigned char* sm) {
    auto As = (unsigned short(*)[256 * 64])(sm);                       // 3 x 32KB
    auto Bs = (unsigned short(*)[128 * 64])(sm + 3 * 256 * 64 * 2);    // 3 x 16KB
    const int tid = threadIdx.x;
    const int w = tid >> 6, lane = tid & 63;
    const int wm = (w >> 1) * 64, wn = (w & 1) * 64;
    const int l31 = lane & 31, lhi = lane >> 5;
    const int sw32 = (l31 >> 1) & 7;
    const int nt = kLen >> 6;

    f32x16 acc[2][2];
    #pragma unroll
    for (int i = 0; i < 2; ++i)
        #pragma unroll
        for (int j = 0; j < 2; ++j) acc[i][j] = (f32x16)(0.0f);

    auto stage = [&](int buf, int k0) {
        #pragma unroll
        for (int p = 0; p < 4; ++p) {
            const int c = p * 512 + tid;
            const int row = c >> 3;
            const int kc = (c & 7) ^ ((row >> 1) & 7);
            __builtin_amdgcn_global_load_lds(
                (const __attribute__((address_space(1))) unsigned int*)
                    (A + (size_t)(tileM + row) * K + k0 + kc * 8),
                (__attribute__((address_space(3))) unsigned int*)&As[buf][c * 8],
                16, 0, 0);
        }
        #pragma unroll
        for (int p = 0; p < 2; ++p) {
            const int c = p * 512 + tid;
            const int row = c >> 3;
            const int kc = (c & 7) ^ ((row >> 1) & 7);
            __builtin_amdgcn_global_load_lds(
                (const __attribute__((address_space(1))) unsigned int*)
                    (W + (size_t)(tileN + row) * K + k0 + kc * 8),
                (__attribute__((address_space(3))) unsigned int*)&Bs[buf][c * 8],
                16, 0, 0);
        }
    };

    stage(0, kStart);
    if (nt > 1) stage(1, kStart + 64);

    int k0 = kStart;
    for (int t = 0; t < nt; ++t, k0 += 64) {
        if (t + 1 < nt) asm volatile("s_waitcnt vmcnt(6) lgkmcnt(0)" ::: "memory");
        else            asm volatile("s_waitcnt vmcnt(0) lgkmcnt(0)" ::: "memory");
        __builtin_amdgcn_s_barrier();
        if (t + 2 < nt) stage((t + 2) % 3, k0 + 128);

        const unsigned short* Ab = &As[t % 3][0];
        const unsigned short* Bb = &Bs[t % 3][0];
        bf16x8 af[4][2], bfv[4][2];
        #pragma unroll
        for (int s = 0; s < 4; ++s) {
            const int slot = (2 * s + lhi) ^ sw32;
            #pragma unroll
            for (int i = 0; i < 2; ++i)
                af[s][i] = *(const bf16x8*)&Ab[(wm + i * 32 + l31) * 64 + slot * 8];
            #pragma unroll
            for (int j = 0; j < 2; ++j)
                bfv[s][j] = *(const bf16x8*)&Bb[(wn + j * 32 + l31) * 64 + slot * 8];
        }
        __builtin_amdgcn_s_setprio(1);
        #pragma unroll
        for (int s = 0; s < 4; ++s)
            #pragma unroll
            for (int i = 0; i < 2; ++i)
                #pragma unroll
                for (int j = 0; j < 2; ++j)
                    acc[i][j] = __builtin_amdgcn_mfma_f32_32x32x16_bf16(af[s][i], bfv[s][j], acc[i][j], 0, 0, 0);
        __builtin_amdgcn_s_setprio(0);
    }

    // C/D 32x32: col = lane&31, row = (reg&3)+8*(reg>>2)+4*(lane>>5)  [m74/m101]
    #pragma unroll
    for (int i = 0; i < 2; ++i) {
        #pragma unroll
        for (int j = 0; j < 2; ++j) {
            const int col = tileN + wn + j * 32 + l31;
            #pragma unroll
            for (int q = 0; q < 4; ++q) {
                const int rbase = tileM + wm + i * 32 + q * 8 + lhi * 4;
                #pragma unroll
                for (int r = 0; r < 4; ++r) {
                    const int row = rbase + r;
                    const size_t off = (size_t)row * N + col;
                    float v = acc[i][j][q * 4 + r];
                    if constexpr (EPI == EPI_PART) {
                        ((float*)outp)[(size_t)zIdx * (size_t)M * (size_t)N + off] = v;
                    } else if constexpr (EPI == EPI_QKV) {
                        float bc = (col < D) ? bias[col] : ((col < 2 * D) ? bias2[col - D] : bias3[col - 2 * D]);
                        v += bc;
                        if (col < 2 * D) v = v > 0.0f ? v + 1.0f : __expf(v);
                        ((float*)outp)[off] = v;
                    } else if constexpr (EPI == EPI_GELU_BF16) {
                        v += bias[col];
                        float gl = 0.5f * v * (1.0f + erff(v * 0.70710678118654752f));
                        ((unsigned short*)outp)[off] = f2bf(gl);
                    }
                }
            }
        }
    }
}

// ---- 128x64-tile bf16 GEMM (out-proj K=1024). Runs as a HALF-block (256 thr,
// lt = tid&255); two tiles per 512-thr block, each half owns 73728 B of LDS.
// Block-wide s_barrier aligns across halves because both run the same nt.
__device__ void n64_phase(const unsigned short* __restrict__ A,
                          const unsigned short* __restrict__ W,
                          float* __restrict__ outp,
                          int M, int N, int K, int tileM, int tileN,
                          unsigned char* sm, int lt) {
    auto As = (unsigned short(*)[128 * 64])(sm);                      // 3 x 16KB
    auto Bs = (unsigned short(*)[64 * 64])(sm + 3 * 128 * 64 * 2);    // 3 x 8KB
    const int w = lt >> 6, lane = lt & 63;
    const int wm = (w >> 1) * 64, wn = (w & 1) * 32;
    const int l31 = lane & 31, lhi = lane >> 5;
    const int sw32 = (l31 >> 1) & 7;
    const int nt = K >> 6;

    f32x16 acc[2];
    #pragma unroll
    for (int i = 0; i < 2; ++i) acc[i] = (f32x16)(0.0f);

    auto stage = [&](int buf, int k0) {
        #pragma unroll
        for (int p = 0; p < 4; ++p) {
            const int c = p * 256 + lt;
            const int row = c >> 3;
            const int kc = (c & 7) ^ ((row >> 1) & 7);
            __builtin_amdgcn_global_load_lds(
                (const __attribute__((address_space(1))) unsigned int*)
                    (A + (size_t)(tileM + row) * K + k0 + kc * 8),
                (__attribute__((address_space(3))) unsigned int*)&As[buf][c * 8],
                16, 0, 0);
        }
        #pragma unroll
        for (int p = 0; p < 2; ++p) {
            const int c = p * 256 + lt;
            const int row = c >> 3;
            const int kc = (c & 7) ^ ((row >> 1) & 7);
            __builtin_amdgcn_global_load_lds(
                (const __attribute__((address_space(1))) unsigned int*)
                    (W + (size_t)(tileN + row) * K + k0 + kc * 8),
                (__attribute__((address_space(3))) unsigned int*)&Bs[buf][c * 8],
                16, 0, 0);
        }
    };

    stage(0, 0);
    if (nt > 1) stage(1, 64);

    int k0 = 0;
    for (int t = 0; t < nt; ++t, k0 += 64) {
        if (t + 1 < nt) asm volatile("s_waitcnt vmcnt(6) lgkmcnt(0)" ::: "memory");
        else            asm volatile("s_waitcnt vmcnt(0) lgkmcnt(0)" ::: "memory");
        __builtin_amdgcn_s_barrier();
        if (t + 2 < nt) stage((t + 2) % 3, k0 + 128);

        const unsigned short* Ab = &As[t % 3][0];
        const unsigned short* Bb = &Bs[t % 3][0];
        bf16x8 af[4][2], bfv[4];
        #pragma unroll
        for (int s = 0; s < 4; ++s) {
            const int slot = (2 * s + lhi) ^ sw32;
            #pragma unroll
            for (int i = 0; i < 2; ++i)
                af[s][i] = *(const bf16x8*)&Ab[(wm + i * 32 + l31) * 64 + slot * 8];
            bfv[s] = *(const bf16x8*)&Bs[t % 3][(wn + l31) * 64 + slot * 8 - 0];
        }
        __builtin_amdgcn_s_setprio(1);
        #pragma unroll
        for (int s = 0; s < 4; ++s)
            #pragma unroll
            for (int i = 0; i < 2; ++i)
                acc[i] = __builtin_amdgcn_mfma_f32_32x32x16_bf16(af[s][i], bfv[s], acc[i], 0, 0, 0);
        __builtin_amdgcn_s_setprio(0);
    }

    #pragma unroll
    for (int i = 0; i < 2; ++i) {
        const int col = tileN + wn + l31;
        #pragma unroll
        for (int q = 0; q < 4; ++q) {
            const int rbase = tileM + wm + i * 32 + q * 8 + lhi * 4;
            #pragma unroll
            for (int r = 0; r < 4; ++r) {
                const int row = rbase + r;
                outp[(size_t)row * N + col] = acc[i][q * 4 + r];
            }
        }
    }
}

struct MegaArgs {
    const float *x;
    const float *Wq, *bq, *Wk, *bk, *Wv, *bv, *Wo, *bo, *W1, *b1, *W2, *b2;
    const float *g1, *be1, *g2, *be2;
    unsigned short *h1, *attn, *gbuf;
    float *x2;
    unsigned short *Wqkvb, *Wob, *W1b, *W2b;
    float *KVc, *Zc, *uni, *out;
};

// ---- THE pipeline: one cooperative launch, 10 phases, 9 grid.sync() ----
__global__ __launch_bounds__(NTHR, 2) void mega(MegaArgs a) {
    cg::grid_group grid = cg::this_grid();
    __shared__ __align__(16) unsigned char SM[147456];   // 144 KB -> 1 block/CU
    const int bid = blockIdx.x, tid = threadIdx.x;
    const int half = tid >> 8, lt = tid & 255;
    float* qkv = a.uni;
    float* parts = a.uni;

    // ---- P0: weight fp32->bf16 cvt (grid-stride, 24 iters/thread) + LN1 ----
    for (int i = bid * NTHR + tid; i < CVT_TOTAL4; i += NBLK * NTHR) {
        const float* s;
        unsigned short* dp;
        if (i < DD4)                 { s = a.Wq + (size_t)i * 4;               dp = a.Wqkvb + (size_t)i * 4; }
        else if (i < 2 * DD4)        { s = a.Wk + (size_t)(i - DD4) * 4;       dp = a.Wqkvb + (size_t)i * 4; }
        else if (i < 3 * DD4)        { s = a.Wv + (size_t)(i - 2 * DD4) * 4;   dp = a.Wqkvb + (size_t)i * 4; }
        else if (i < 4 * DD4)        { s = a.Wo + (size_t)(i - 3 * DD4) * 4;   dp = a.Wob + (size_t)(i - 3 * DD4) * 4; }
        else if (i < 4 * DD4 + FD4)  { s = a.W1 + (size_t)(i - 4 * DD4) * 4;   dp = a.W1b + (size_t)(i - 4 * DD4) * 4; }
        else                         { s = a.W2 + (size_t)(i - 4 * DD4 - FD4) * 4; dp = a.W2b + (size_t)(i - 4 * DD4 - FD4) * 4; }
        float4 v = *(const float4*)s;
        ushort4 o = { f2bf(v.x), f2bf(v.y), f2bf(v.z), f2bf(v.w) };
        *(ushort4*)dp = o;
    }
    {
        float* sw = (float*)SM;  float* ssw = sw + 8;   // [2][4] each
        for (int r0 = 0; r0 < 8; r0 += 2) {
            const int row = bid * 8 + r0 + half;
            float4 v = ((const float4*)(a.x + (size_t)row * D))[lt];
            float s = v.x + v.y + v.z + v.w;
            float ss = v.x * v.x + v.y * v.y + v.z * v.z + v.w * v.w;
            #pragma unroll
            for (int off = 32; off > 0; off >>= 1) { s += __shfl_down(s, off); ss += __shfl_down(ss, off); }
            if ((lt & 63) == 0) { sw[half * 4 + (lt >> 6)] = s; ssw[half * 4 + (lt >> 6)] = ss; }
            __syncthreads();
            s  = sw[half * 4] + sw[half * 4 + 1] + sw[half * 4 + 2] + sw[half * 4 + 3];
            ss = ssw[half * 4] + ssw[half * 4 + 1] + ssw[half * 4 + 2] + ssw[half * 4 + 3];
            const float mu = s * (1.0f / D);
            const float rs = rsqrtf(ss * (1.0f / D) - mu * mu + 1e-5f);
            float4 gv = ((const float4*)a.g1)[lt];
            float4 bv = ((const float4*)a.be1)[lt];
            ushort4 o = { f2bf((v.x - mu) * rs * gv.x + bv.x), f2bf((v.y - mu) * rs * gv.y + bv.y),
                          f2bf((v.z - mu) * rs * gv.z + bv.z), f2bf((v.w - mu) * rs * gv.w + bv.w) };
            ((ushort4*)(a.h1 + (size_t)row * D))[lt] = o;
            __syncthreads();
        }
    }
    grid.sync();

    // ---- P1: QKV projection, 192 tiles (8 x 24) ----
    if (bid < 192)
        gemm_phase<EPI_QKV>(a.h1, a.Wqkvb, a.bq, a.bk, a.bv, qkv, S, 3 * D, D,
                            (bid & 7) * 256, (bid >> 3) * 128, 0, D, 0, SM);
    grid.sync();

    // ---- P2: per-chunk K^T V sums + z sums (2 units/block) ----
    {
        const int u = bid * 2 + half, c = u & (NC - 1), h = u >> 5;
        float* Kc = (float*)(SM + half * 32768);
        float* Vc = Kc + CHK * HD;
        const int s0 = c * CHK;
        #pragma unroll
        for (int p = 0; p < 4; ++p) {
            int cc = p * 256 + lt;
            int t = cc >> 4, dp = (cc & 15) * 4;
            *(float4*)&Kc[t * HD + dp] = *(const float4*)(qkv + (size_t)(s0 + t) * QS + D + h * HD + dp);
            *(float4*)&Vc[t * HD + dp] = *(const float4*)(qkv + (size_t)(s0 + t) * QS + 2 * D + h * HD + dp);
        }
        __syncthreads();
        const int d = lt >> 2, e0 = (lt & 3) * 16;
        float acc[16];
        #pragma unroll
        for (int j = 0; j < 16; ++j) acc[j] = 0.0f;
        float zacc = 0.0f;
        for (int t = 0; t < CHK; ++t) {
            float kv = Kc[t * HD + d];
            zacc += kv;
            #pragma unroll
            for (int j = 0; j < 16; ++j) acc[j] += kv * Vc[t * HD + e0 + j];
        }
        float* op = a.KVc + ((size_t)(h * NC + c) * HD + d) * HD + e0;
        #pragma unroll
        for (int j = 0; j < 16; ++j) op[j] = acc[j];
        if ((lt & 3) == 0) a.Zc[(size_t)(h * NC + c) * HD + d] = zacc;
    }
    grid.sync();

    // ---- P3: exclusive prefix over chunks (load-all / scan / store-all) ----
    {
        const int flat = bid * NTHR + tid;
        if (flat < H * HD * HD) {
            const int h = flat >> 12, elem = flat & 4095;
            size_t base = (size_t)h * NC * (HD * HD) + elem;
            float v[NC];
            #pragma unroll
            for (int c = 0; c < NC; ++c) v[c] = a.KVc[base + (size_t)c * (HD * HD)];
            float run = 0.0f;
            #pragma unroll
            for (int c = 0; c < NC; ++c) { float t = v[c]; v[c] = run; run += t; }
            #pragma unroll
            for (int c = 0; c < NC; ++c) a.KVc[base + (size_t)c * (HD * HD)] = v[c];
        }
        const int zi = flat - H * HD * HD;
        if (zi >= 0 && zi < H * HD) {
            const int h = zi >> 6, d = zi & 63;
            size_t zb = (size_t)h * NC * HD + d;
            float z[NC];
            #pragma unroll
            for (int c = 0; c < NC; ++c) z[c] = a.Zc[zb + (size_t)c * HD];
            float zr = 0.0f;
            #pragma unroll
            for (int c = 0; c < NC; ++c) { float t = z[c]; z[c] = zr; zr += t; }
            #pragma unroll
            for (int c = 0; c < NC; ++c) a.Zc[zb + (size_t)c * HD] = z[c];
        }
    }
    grid.sync();

    // ---- P4: attention output (2 units/block; stride-68 pad kills bank conflicts) ----
    {
        const int u = bid * 2 + half, c = u & (NC - 1), h = u >> 5;
        float* Qc = (float*)(SM + half * 69888);   // [64][68]
        float* Kv = Qc + 64 * 68;                  // K, later V   [64][68]
        float* Sc = Kv + 64 * 68;                  // [64][68]
        float* Pre = Sc + 64 * 68;                 // [64][64]
        float* zp = Pre + 4096;                    // [64]
        float* den = zp + 64;                      // [64]
        const int s0 = c * CHK;
        #pragma unroll
        for (int p = 0; p < 4; ++p) {
            int cc = p * 256 + lt;
            int t = cc >> 4, dp = (cc & 15) * 4;
            *(float4*)&Qc[t * 68 + dp] = *(const float4*)(qkv + (size_t)(s0 + t) * QS + h * HD + dp);
            *(float4*)&Kv[t * 68 + dp] = *(const float4*)(qkv + (size_t)(s0 + t) * QS + D + h * HD + dp);
            ((float4*)Pre)[cc] = *(const float4*)(a.KVc + (size_t)(h * NC + c) * (HD * HD) + cc * 4);
        }
        if (lt < HD) zp[lt] = a.Zc[(size_t)(h * NC + c) * HD + lt];
        __syncthreads();

        const int tt = lt >> 2, i0 = (lt & 3) * 16;
        for (int i = i0; i < i0 + 16; ++i) {
            float sv = 0.0f;
            for (int d2 = 0; d2 < HD; ++d2) sv += Qc[tt * 68 + d2] * Kv[i * 68 + d2];
            Sc[tt * 68 + i] = (i <= tt) ? sv : 0.0f;
        }
        __syncthreads();

        if (lt < CHK) {
            float dv = 1e-6f;
            for (int d2 = 0; d2 < HD; ++d2) dv += Qc[lt * 68 + d2] * zp[d2];
            for (int i = 0; i < CHK; ++i) dv += Sc[lt * 68 + i];
            den[lt] = dv;
        }
        #pragma unroll
        for (int p = 0; p < 4; ++p) {
            int cc = p * 256 + lt;
            int t = cc >> 4, dp = (cc & 15) * 4;
            *(float4*)&Kv[t * 68 + dp] = *(const float4*)(qkv + (size_t)(s0 + t) * QS + 2 * D + h * HD + dp);
        }
        __syncthreads();

        float o[16];
        #pragma unroll
        for (int j = 0; j < 16; ++j) o[j] = 0.0f;
        for (int d2 = 0; d2 < HD; ++d2) {
            float qv = Qc[tt * 68 + d2];
            float sv = Sc[tt * 68 + d2];
            #pragma unroll
            for (int j = 0; j < 16; ++j)
                o[j] += qv * Pre[d2 * HD + i0 + j] + sv * Kv[d2 * 68 + i0 + j];
        }
        const float inv = 1.0f / den[tt];
        unsigned short* op = a.attn + (size_t)(s0 + tt) * D + h * HD + i0;
        #pragma unroll
        for (int j0 = 0; j0 < 16; j0 += 4) {
            ushort4 ov = { f2bf(o[j0] * inv), f2bf(o[j0 + 1] * inv),
                           f2bf(o[j0 + 2] * inv), f2bf(o[j0 + 3] * inv) };
            *(ushort4*)(op + j0) = ov;
        }
    }
    grid.sync();

    // ---- P5: out-proj 128x64 tiles, K=1024 (2 tiles/block, 128 blocks) ----
    if (bid < 128) {
        const int u = bid * 2 + half;
        n64_phase(a.attn, a.Wob, parts, S, D, D,
                  (u & 15) * 128, (u >> 4) * 64, SM + half * 73728, lt);
    }
    grid.sync();

    // ---- P6: bias + residual(x) + LayerNorm2 -> x2 (fp32), h1 (bf16) ----
    {
        float* sw = (float*)SM;  float* ssw = sw + 8;
        for (int r0 = 0; r0 < 8; r0 += 2) {
            const int row = bid * 8 + r0 + half;
            const size_t i4 = (size_t)row * 256 + lt;
            float4 aa = ((const float4*)parts)[i4];
            float4 bi = ((const float4*)a.bo)[lt];
            float4 r = ((const float4*)a.x)[i4];
            aa.x += bi.x + r.x; aa.y += bi.y + r.y; aa.z += bi.z + r.z; aa.w += bi.w + r.w;
            ((float4*)a.x2)[i4] = aa;
            float s = aa.x + aa.y + aa.z + aa.w;
            float ss = aa.x * aa.x + aa.y * aa.y + aa.z * aa.z + aa.w * aa.w;
            #pragma unroll
            for (int off = 32; off > 0; off >>= 1) { s += __shfl_down(s, off); ss += __shfl_down(ss, off); }
            if ((lt & 63) == 0) { sw[half * 4 + (lt >> 6)] = s; ssw[half * 4 + (lt >> 6)] = ss; }
            __syncthreads();
            s  = sw[half * 4] + sw[half * 4 + 1] + sw[half * 4 + 2] + sw[half * 4 + 3];
            ss = ssw[half * 4] + ssw[half * 4 + 1] + ssw[half * 4 + 2] + ssw[half * 4 + 3];
            const float mu = s * (1.0f / D);
            const float rs = rsqrtf(ss * (1.0f / D) - mu * mu + 1e-5f);
            float4 gv = ((const float4*)a.g2)[lt];
            float4 bv = ((const float4*)a.be2)[lt];
            ushort4 o = { f2bf((aa.x - mu) * rs * gv.x + bv.x), f2bf((aa.y - mu) * rs * gv.y + bv.y),
                          f2bf((aa.z - mu) * rs * gv.z + bv.z), f2bf((aa.w - mu) * rs * gv.w + bv.w) };
            ((ushort4*)(a.h1 + (size_t)row * D))[lt] = o;
            __syncthreads();
        }
    }
    grid.sync();

    // ---- P7: FFN1 (8 x 32 = 256 tiles), GELU fused, bf16 out ----
    gemm_phase<EPI_GELU_BF16>(a.h1, a.W1b, a.b1, nullptr, nullptr, a.gbuf, S, FF, D,
                              (bid & 7) * 256, (bid >> 3) * 128, 0, D, 0, SM);
    grid.sync();

    // ---- P8: FFN2 split-K=4 (8 x 8 x 4 = 256 units) -> parts ----
    gemm_phase<EPI_PART>(a.gbuf, a.W2b, nullptr, nullptr, nullptr, parts, S, D, FF,
                         (bid & 7) * 256, ((bid >> 3) & 7) * 128, (bid >> 6) * 1024,
                         1024, bid >> 6, SM);
    grid.sync();

    // ---- P9: reduce 4 partials + bias + residual(x2) -> out ----
    {
        const int total4 = S * D / 4;
        for (int i = bid * NTHR + tid; i < total4; i += NBLK * NTHR) {
            float4 aa = ((const float4*)parts)[i];
            #pragma unroll
            for (int z = 1; z < 4; ++z) {
                float4 p = ((const float4*)parts)[(size_t)z * total4 + i];
                aa.x += p.x; aa.y += p.y; aa.z += p.z; aa.w += p.w;
            }
            float4 b = ((const float4*)a.b2)[i & 255];
            float4 r = ((const float4*)a.x2)[i];
            aa.x += b.x + r.x; aa.y += b.y + r.y; aa.z += b.z + r.z; aa.w += b.w + r.w;
            ((float4*)a.out)[i] = aa;
        }
    }
}

// ---------------- launcher: ONE cooperative launch ----------------
extern "C" void kernel_launch(void* const* d_in, const int* in_sizes, int n_in,
                              void* d_out, int out_size, void* d_ws, size_t ws_size,
                              hipStream_t stream) {
    char* wsp = (char*)d_ws;
    auto alloc = [&](size_t bytes) {
        char* p = wsp;
        wsp += (bytes + 255) & ~(size_t)255;
        return p;
    };
    unsigned short* h1   = (unsigned short*)alloc((size_t)S * D * 2);
    unsigned short* attn = (unsigned short*)alloc((size_t)S * D * 2);
    unsigned short* gbuf = (unsigned short*)alloc((size_t)S * FF * 2);
    float* x2 = (float*)alloc((size_t)S * D * 4);
    unsigned short* Wqkvb = (unsigned short*)alloc((size_t)3 * D * D * 2);
    unsigned short* Wob   = (unsigned short*)alloc((size_t)D * D * 2);
    unsigned short* W1b   = (unsigned short*)alloc((size_t)FF * D * 2);
    unsigned short* W2b   = (unsigned short*)alloc((size_t)D * FF * 2);
    float* KVc = (float*)alloc((size_t)H * NC * HD * HD * 4);
    float* Zc  = (float*)alloc((size_t)H * NC * HD * 4);
    float* uni = (float*)alloc((size_t)32 * 1024 * 1024);   // qkv / parts union

    MegaArgs a;
    a.x   = (const float*)d_in[0];
    a.Wq  = (const float*)d_in[1];  a.bq  = (const float*)d_in[2];
    a.Wk  = (const float*)d_in[3];  a.bk  = (const float*)d_in[4];
    a.Wv  = (const float*)d_in[5];  a.bv  = (const float*)d_in[6];
    a.Wo  = (const float*)d_in[7];  a.bo  = (const float*)d_in[8];
    a.W1  = (const float*)d_in[9];  a.b1  = (const float*)d_in[10];
    a.W2  = (const float*)d_in[11]; a.b2  = (const float*)d_in[12];
    a.g1  = (const float*)d_in[13]; a.be1 = (const float*)d_in[14];
    a.g2  = (const float*)d_in[15]; a.be2 = (const float*)d_in[16];
    a.h1 = h1; a.attn = attn; a.gbuf = gbuf; a.x2 = x2;
    a.Wqkvb = Wqkvb; a.Wob = Wob; a.W1b = W1b; a.W2b = W2b;
    a.KVc = KVc; a.Zc = Zc; a.uni = uni; a.out = (float*)d_out;

    void* kargs[] = { &a };
    hipLaunchCooperativeKernel((const void*)mega, dim3(NBLK), dim3(NTHR),
                               kargs, 0, stream);
}

// Round 8
// 293.573 us; speedup vs baseline: 1.9698x; 1.9698x over previous
//
#include <hip/hip_runtime.h>
#include <hip/hip_bf16.h>
#include <math.h>

// Problem constants (B=1)
constexpr int S  = 2048;
constexpr int D  = 1024;
constexpr int H  = 16;
constexpr int HD = 64;
constexpr int FF = 4096;
constexpr int NC  = 32;   // number of chunks for linear attention
constexpr int CHK = 64;   // chunk length (timesteps)
constexpr int QS  = 3 * D; // fused qkv row stride

typedef __attribute__((ext_vector_type(8))) short bf16x8;
typedef __attribute__((ext_vector_type(16))) float f32x16;

__device__ inline unsigned short f2bf(float f) {
    unsigned int u = __float_as_uint(f);
    u = (u + 0x7FFFu + ((u >> 16) & 1u)) >> 16;   // RNE
    return (unsigned short)u;
}

// ---------------- fused weight-convert (fp32->bf16) + LayerNorm1, ONE launch ----------------
constexpr int DD4 = D * D / 4;       // 262144
constexpr int FD4 = FF * D / 4;      // 1048576
constexpr int CVT_TOTAL4 = 4 * DD4 + 2 * FD4;   // 3145728
constexpr int CVT_BLOCKS = CVT_TOTAL4 / 256;    // 12288

// blocks [0, S): LayerNorm of row blockIdx.x; blocks [S, S+CVT_BLOCKS): weight cvt
__global__ __launch_bounds__(256) void cvt_ln(const float* __restrict__ x,
                                              const float* __restrict__ g,
                                              const float* __restrict__ b,
                                              unsigned short* __restrict__ lnout,
                                              const float* __restrict__ Wq,
                                              const float* __restrict__ Wk,
                                              const float* __restrict__ Wv,
                                              const float* __restrict__ Wo,
                                              const float* __restrict__ W1,
                                              const float* __restrict__ W2,
                                              unsigned short* __restrict__ Wqkvb,
                                              unsigned short* __restrict__ Wob,
                                              unsigned short* __restrict__ W1b,
                                              unsigned short* __restrict__ W2b) {
    const int tid = threadIdx.x;
    if (blockIdx.x >= S) {
        int i = (blockIdx.x - S) * 256 + tid;
        const float* s;
        unsigned short* dp;
        if (i < DD4)                 { s = Wq + (size_t)i * 4;               dp = Wqkvb + (size_t)i * 4; }
        else if (i < 2 * DD4)        { s = Wk + (size_t)(i - DD4) * 4;       dp = Wqkvb + (size_t)i * 4; }
        else if (i < 3 * DD4)        { s = Wv + (size_t)(i - 2 * DD4) * 4;   dp = Wqkvb + (size_t)i * 4; }
        else if (i < 4 * DD4)        { s = Wo + (size_t)(i - 3 * DD4) * 4;   dp = Wob + (size_t)(i - 3 * DD4) * 4; }
        else if (i < 4 * DD4 + FD4)  { s = W1 + (size_t)(i - 4 * DD4) * 4;   dp = W1b + (size_t)(i - 4 * DD4) * 4; }
        else                         { s = W2 + (size_t)(i - 4 * DD4 - FD4) * 4; dp = W2b + (size_t)(i - 4 * DD4 - FD4) * 4; }
        float4 v = *(const float4*)s;
        ushort4 o = { f2bf(v.x), f2bf(v.y), f2bf(v.z), f2bf(v.w) };
        *(ushort4*)dp = o;
        return;
    }
    const int row = blockIdx.x;
    float4 v = ((const float4*)(x + (size_t)row * D))[tid];
    float s  = v.x + v.y + v.z + v.w;
    float ss = v.x*v.x + v.y*v.y + v.z*v.z + v.w*v.w;
    #pragma unroll
    for (int off = 32; off > 0; off >>= 1) {
        s  += __shfl_down(s, off);
        ss += __shfl_down(ss, off);
    }
    __shared__ float sw[4], ssw[4];
    if ((tid & 63) == 0) { sw[tid >> 6] = s; ssw[tid >> 6] = ss; }
    __syncthreads();
    s  = sw[0] + sw[1] + sw[2] + sw[3];
    ss = ssw[0] + ssw[1] + ssw[2] + ssw[3];
    const float mu = s * (1.0f / D);
    const float rs = rsqrtf(ss * (1.0f / D) - mu * mu + 1e-5f);
    float4 gv = ((const float4*)g)[tid];
    float4 bv = ((const float4*)b)[tid];
    ushort4 o = { f2bf((v.x - mu) * rs * gv.x + bv.x),
                  f2bf((v.y - mu) * rs * gv.y + bv.y),
                  f2bf((v.z - mu) * rs * gv.z + bv.z),
                  f2bf((v.w - mu) * rs * gv.w + bv.w) };
    ((ushort4*)(lnout + (size_t)row * D))[tid] = o;
}

// ---------------- reduce (KS copies) + bias + residual + LayerNorm ----------------
template <int KS>
__global__ __launch_bounds__(256) void reduce_ln(const float* __restrict__ part,
                                                 const float* __restrict__ bias,
                                                 const float* __restrict__ res,
                                                 float* __restrict__ x2,
                                                 const float* __restrict__ g,
                                                 const float* __restrict__ b,
                                                 unsigned short* __restrict__ out) {
    const int row = blockIdx.x, tid = threadIdx.x;
    const size_t i4 = (size_t)row * 256 + tid;       // float4 index into SxD
    float4 a = ((const float4*)part)[i4];
    #pragma unroll
    for (int z = 1; z < KS; ++z) {
        float4 p = ((const float4*)part)[(size_t)z * S * 256 + i4];
        a.x += p.x; a.y += p.y; a.z += p.z; a.w += p.w;
    }
    float4 bi = ((const float4*)bias)[tid];
    float4 r  = ((const float4*)res)[i4];
    a.x += bi.x + r.x; a.y += bi.y + r.y; a.z += bi.z + r.z; a.w += bi.w + r.w;
    ((float4*)x2)[i4] = a;
    float s  = a.x + a.y + a.z + a.w;
    float ss = a.x*a.x + a.y*a.y + a.z*a.z + a.w*a.w;
    #pragma unroll
    for (int off = 32; off > 0; off >>= 1) {
        s  += __shfl_down(s, off);
        ss += __shfl_down(ss, off);
    }
    __shared__ float sw[4], ssw[4];
    if ((tid & 63) == 0) { sw[tid >> 6] = s; ssw[tid >> 6] = ss; }
    __syncthreads();
    s  = sw[0] + sw[1] + sw[2] + sw[3];
    ss = ssw[0] + ssw[1] + ssw[2] + ssw[3];
    const float mu = s * (1.0f / D);
    const float rs = rsqrtf(ss * (1.0f / D) - mu * mu + 1e-5f);
    float4 gv = ((const float4*)g)[tid];
    float4 bv = ((const float4*)b)[tid];
    ushort4 o = { f2bf((a.x - mu) * rs * gv.x + bv.x),
                  f2bf((a.y - mu) * rs * gv.y + bv.y),
                  f2bf((a.z - mu) * rs * gv.z + bv.z),
                  f2bf((a.w - mu) * rs * gv.w + bv.w) };
    ((ushort4*)(out + (size_t)row * D))[tid] = o;
}

// ---------------- split-K reduce (final output, no LN) ----------------
template <int KS>
__global__ __launch_bounds__(256) void reduce_bias_res(const float* __restrict__ part,
                                                       const float* __restrict__ bias,
                                                       const float* __restrict__ res,
                                                       float* __restrict__ out,
                                                       int N4, int total4) {
    int i = blockIdx.x * 256 + threadIdx.x;
    if (i >= total4) return;
    float4 a = ((const float4*)part)[i];
    #pragma unroll
    for (int z = 1; z < KS; ++z) {
        float4 p = ((const float4*)part)[(size_t)z * total4 + i];
        a.x += p.x; a.y += p.y; a.z += p.z; a.w += p.w;
    }
    float4 b = ((const float4*)bias)[i % N4];
    float4 r = ((const float4*)res)[i];
    a.x += b.x + r.x; a.y += b.y + r.y; a.z += b.z + r.z; a.w += b.w + r.w;
    ((float4*)out)[i] = a;
}

// Epilogue variants
enum { EPI_F32 = 0, EPI_QKV = 1, EPI_GELU_BF16 = 2, EPI_PART = 3, EPI_BIAS_RES = 4 };

// ---------------- bf16 MFMA GEMM, 256x128 tile (QKV / FFN1 / FFN2 split-K) ----------------
// BK=64, 512 threads (8 waves 4Mx2N, 64x64 wave tiles), v_mfma_f32_32x32x16_bf16.
// DEPTH-3 LDS pipeline (144 KB, 1 block/CU), COUNTED vmcnt(6) (T3+T4, m218).
// NEW (R8): m201-style 4-PHASE cadence per K-tile. Phase s = { ds_read K-slice s
// (4 reads) ; stage-issue 3 of tile t+2's 6 loads (phases 0-1) ; s_barrier ;
// lgkmcnt(0) ; setprio(1) 4 MFMA setprio(0) }. Barriers only ADDED at uniform
// points -> no new hazards. WAR proof: every wave's phase-3 lgkmcnt(0) precedes
// the tile-top barrier, so all prior-tile ds_reads are drained chip-wide before
// the (t+2)%3 == (t-1)%3 buffer is re-staged (stage-issue follows that barrier).
// XOR-swizzled LDS (measured SQ_LDS_BANK_CONFLICT == 0): slot p of row r holds
// global chunk p ^ ((r>>1)&7); XOR applied to GLOBAL source index.
// C/D 32x32 layout [m74/m101]: col = lane&31, row = (reg&3)+8*(reg>>2)+4*(lane>>5).
template <int EPI>
__global__ __launch_bounds__(512, 2) void gemm_bt2(const unsigned short* __restrict__ A,
                                                   const unsigned short* __restrict__ W,
                                                   const float* __restrict__ bias,
                                                   const float* __restrict__ bias2,
                                                   const float* __restrict__ bias3,
                                                   void* __restrict__ outp,
                                                   int M, int N, int K, int kSplit) {
    __shared__ unsigned short As[3][256 * 64];   // 96 KB
    __shared__ unsigned short Bs[3][128 * 64];   // 48 KB
    const int tid   = threadIdx.x;
    const int tileM = blockIdx.x * 256;
    const int tileN = blockIdx.y * 128;
    const int w    = tid >> 6, lane = tid & 63;
    const int wm   = (w >> 1) * 64, wn = (w & 1) * 64;
    const int l31  = lane & 31, lhi = lane >> 5;
    const int sw32 = (l31 >> 1) & 7;
    const int kLen   = K / kSplit;
    const int kStart = blockIdx.z * kLen;
    const int nt     = kLen >> 6;

    f32x16 acc[2][2];
    #pragma unroll
    for (int i = 0; i < 2; ++i)
        #pragma unroll
        for (int j = 0; j < 2; ++j) acc[i][j] = (f32x16)(0.0f);

    // one A-chunk-pair or B-chunk group (512 lanes x 16B each)
    auto stageA = [&](int buf, int k0, int p) {
        const int c   = p * 512 + tid;
        const int row = c >> 3;
        const int kc  = (c & 7) ^ ((row >> 1) & 7);
        __builtin_amdgcn_global_load_lds(
            (const __attribute__((address_space(1))) unsigned int*)
                (A + (size_t)(tileM + row) * K + k0 + kc * 8),
            (__attribute__((address_space(3))) unsigned int*)&As[buf][c * 8],
            16, 0, 0);
    };
    auto stageB = [&](int buf, int k0, int p) {
        const int c   = p * 512 + tid;
        const int row = c >> 3;
        const int kc  = (c & 7) ^ ((row >> 1) & 7);
        __builtin_amdgcn_global_load_lds(
            (const __attribute__((address_space(1))) unsigned int*)
                (W + (size_t)(tileN + row) * K + k0 + kc * 8),
            (__attribute__((address_space(3))) unsigned int*)&Bs[buf][c * 8],
            16, 0, 0);
    };
    auto stageAll = [&](int buf, int k0) {
        stageA(buf, k0, 0); stageA(buf, k0, 1); stageA(buf, k0, 2); stageA(buf, k0, 3);
        stageB(buf, k0, 0); stageB(buf, k0, 1);
    };

    stageAll(0, kStart);
    if (nt > 1) stageAll(1, kStart + 64);

    int k0 = kStart;
    for (int t = 0; t < nt; ++t, k0 += 64) {
        // tile t landed iff all loads except tile t+1's 6 have retired
        if (t + 1 < nt) asm volatile("s_waitcnt vmcnt(6) lgkmcnt(0)" ::: "memory");
        else            asm volatile("s_waitcnt vmcnt(0) lgkmcnt(0)" ::: "memory");
        __builtin_amdgcn_s_barrier();                  // buffer t ready for ALL waves

        const unsigned short* Ab = &As[t % 3][0];
        const unsigned short* Bb = &Bs[t % 3][0];
        const int pfBuf = (t + 2) % 3;
        const bool pf = (t + 2 < nt);
        #pragma unroll
        for (int s = 0; s < 4; ++s) {
            const int slot = (2 * s + lhi) ^ sw32;
            bf16x8 a0 = *(const bf16x8*)&Ab[(wm      + l31) * 64 + slot * 8];
            bf16x8 a1 = *(const bf16x8*)&Ab[(wm + 32 + l31) * 64 + slot * 8];
            bf16x8 b0 = *(const bf16x8*)&Bb[(wn      + l31) * 64 + slot * 8];
            bf16x8 b1 = *(const bf16x8*)&Bb[(wn + 32 + l31) * 64 + slot * 8];
            if (pf && s == 0) { stageA(pfBuf, k0 + 128, 0); stageA(pfBuf, k0 + 128, 1); stageB(pfBuf, k0 + 128, 0); }
            if (pf && s == 1) { stageA(pfBuf, k0 + 128, 2); stageA(pfBuf, k0 + 128, 3); stageB(pfBuf, k0 + 128, 1); }
            __builtin_amdgcn_s_barrier();              // phase cadence (perf-only)
            asm volatile("s_waitcnt lgkmcnt(0)" ::: "memory");
            __builtin_amdgcn_s_setprio(1);
            acc[0][0] = __builtin_amdgcn_mfma_f32_32x32x16_bf16(a0, b0, acc[0][0], 0, 0, 0);
            acc[0][1] = __builtin_amdgcn_mfma_f32_32x32x16_bf16(a0, b1, acc[0][1], 0, 0, 0);
            acc[1][0] = __builtin_amdgcn_mfma_f32_32x32x16_bf16(a1, b0, acc[1][0], 0, 0, 0);
            acc[1][1] = __builtin_amdgcn_mfma_f32_32x32x16_bf16(a1, b1, acc[1][1], 0, 0, 0);
            __builtin_amdgcn_s_setprio(0);
        }
    }

    #pragma unroll
    for (int i = 0; i < 2; ++i) {
        #pragma unroll
        for (int j = 0; j < 2; ++j) {
            const int col = tileN + wn + j * 32 + l31;
            #pragma unroll
            for (int q = 0; q < 4; ++q) {
                const int rbase = tileM + wm + i * 32 + q * 8 + lhi * 4;
                #pragma unroll
                for (int r = 0; r < 4; ++r) {
                    const int row = rbase + r;
                    const size_t off = (size_t)row * N + col;
                    float v = acc[i][j][q * 4 + r];
                    if constexpr (EPI == EPI_PART) {
                        ((float*)outp)[(size_t)blockIdx.z * (size_t)M * (size_t)N + off] = v;
                    } else if constexpr (EPI == EPI_QKV) {
                        float bc = (col < D) ? bias[col] : ((col < 2 * D) ? bias2[col - D] : bias3[col - 2 * D]);
                        v += bc;
                        if (col < 2 * D) v = v > 0.0f ? v + 1.0f : __expf(v);
                        ((float*)outp)[off] = v;
                    } else if constexpr (EPI == EPI_GELU_BF16) {
                        v += bias[col];
                        float gl = 0.5f * v * (1.0f + erff(v * 0.70710678118654752f));
                        ((unsigned short*)outp)[off] = f2bf(gl);
                    } else {
                        v += bias[col];
                        ((float*)outp)[off] = v;
                    }
                }
            }
        }
    }
}

// ---------------- bf16 MFMA GEMM, 128x64 tile (out-proj only, K=1024) ----------------
// 256 threads (4 waves 2Mx2N, 64x32 wave tiles), depth-3 counted-vmcnt schedule,
// same swizzle. LDS 72 KB -> 2 blocks/CU; grid 16x16=256. Kept ONLY for K=1024
// out-proj (R4: at K=4096 it measured 60 us vs <40.6 for 256x128 split-K).
template <int EPI>
__global__ __launch_bounds__(256, 2) void gemm_n64(const unsigned short* __restrict__ A,
                                                   const unsigned short* __restrict__ W,
                                                   const float* __restrict__ bias,
                                                   const float* __restrict__ res,
                                                   void* __restrict__ outp,
                                                   int M, int N, int K) {
    __shared__ unsigned short As[3][128 * 64];   // 48 KB
    __shared__ unsigned short Bs[3][64 * 64];    // 24 KB
    const int tid   = threadIdx.x;
    const int tileM = blockIdx.x * 128;
    const int tileN = blockIdx.y * 64;
    const int w    = tid >> 6, lane = tid & 63;
    const int wm   = (w >> 1) * 64, wn = (w & 1) * 32;
    const int l31  = lane & 31, lhi = lane >> 5;
    const int sw32 = (l31 >> 1) & 7;
    const int nt   = K >> 6;

    f32x16 acc[2];
    #pragma unroll
    for (int i = 0; i < 2; ++i) acc[i] = (f32x16)(0.0f);

    auto stage = [&](int buf, int k0) {
        #pragma unroll
        for (int p = 0; p < 4; ++p) {                  // A: 128x64 = 1024 16B chunks
            const int c   = p * 256 + tid;
            const int row = c >> 3;
            const int kc  = (c & 7) ^ ((row >> 1) & 7);
            __builtin_amdgcn_global_load_lds(
                (const __attribute__((address_space(1))) unsigned int*)
                    (A + (size_t)(tileM + row) * K + k0 + kc * 8),
                (__attribute__((address_space(3))) unsigned int*)&As[buf][c * 8],
                16, 0, 0);
        }
        #pragma unroll
        for (int p = 0; p < 2; ++p) {                  // B: 64x64 = 512 16B chunks
            const int c   = p * 256 + tid;
            const int row = c >> 3;
            const int kc  = (c & 7) ^ ((row >> 1) & 7);
            __builtin_amdgcn_global_load_lds(
                (const __attribute__((address_space(1))) unsigned int*)
                    (W + (size_t)(tileN + row) * K + k0 + kc * 8),
                (__attribute__((address_space(3))) unsigned int*)&Bs[buf][c * 8],
                16, 0, 0);
        }
    };

    stage(0, 0);
    if (nt > 1) stage(1, 64);

    int k0 = 0;
    for (int t = 0; t < nt; ++t, k0 += 64) {
        if (t + 1 < nt) asm volatile("s_waitcnt vmcnt(6) lgkmcnt(0)" ::: "memory");
        else            asm volatile("s_waitcnt vmcnt(0) lgkmcnt(0)" ::: "memory");
        __builtin_amdgcn_s_barrier();
        if (t + 2 < nt) stage((t + 2) % 3, k0 + 128);

        const unsigned short* Ab = &As[t % 3][0];
        const unsigned short* Bb = &Bs[t % 3][0];
        bf16x8 af[4][2], bfv[4];
        #pragma unroll
        for (int s = 0; s < 4; ++s) {
            const int slot = (2 * s + lhi) ^ sw32;
            #pragma unroll
            for (int i = 0; i < 2; ++i)
                af[s][i] = *(const bf16x8*)&Ab[(wm + i * 32 + l31) * 64 + slot * 8];
            bfv[s] = *(const bf16x8*)&Bb[(wn + l31) * 64 + slot * 8];
        }
        __builtin_amdgcn_s_setprio(1);
        #pragma unroll
        for (int s = 0; s < 4; ++s)
            #pragma unroll
            for (int i = 0; i < 2; ++i)
                acc[i] = __builtin_amdgcn_mfma_f32_32x32x16_bf16(af[s][i], bfv[s], acc[i], 0, 0, 0);
        __builtin_amdgcn_s_setprio(0);
    }

    #pragma unroll
    for (int i = 0; i < 2; ++i) {
        const int col = tileN + wn + l31;
        #pragma unroll
        for (int q = 0; q < 4; ++q) {
            const int rbase = tileM + wm + i * 32 + q * 8 + lhi * 4;
            #pragma unroll
            for (int r = 0; r < 4; ++r) {
                const int row = rbase + r;
                const size_t off = (size_t)row * N + col;
                float v = acc[i][q * 4 + r];
                if constexpr (EPI == EPI_BIAS_RES) {
                    v += bias[col] + res[off];
                    ((float*)outp)[off] = v;
                } else {                                // EPI_PART: raw fp32
                    ((float*)outp)[off] = v;
                }
            }
        }
    }
}

// ---------------- linear attention, chunked causal scan (fp32) ----------------
__global__ __launch_bounds__(256) void attn_chunk_sums(const float* __restrict__ qkv,
                                                       float* __restrict__ KVc,
                                                       float* __restrict__ Zc) {
    const int c = blockIdx.x, h = blockIdx.y, tid = threadIdx.x;
    __shared__ float Kc[CHK * HD], Vc[CHK * HD];
    const int s0 = c * CHK;
    #pragma unroll
    for (int p = 0; p < 4; ++p) {
        int cc = p * 256 + tid;
        int t = cc >> 4, dp = (cc & 15) * 4;
        *(float4*)&Kc[t * HD + dp] = *(const float4*)(qkv + (size_t)(s0 + t) * QS + D     + h * HD + dp);
        *(float4*)&Vc[t * HD + dp] = *(const float4*)(qkv + (size_t)(s0 + t) * QS + 2 * D + h * HD + dp);
    }
    __syncthreads();
    const int d = tid >> 2, e0 = (tid & 3) * 16;
    float acc[16];
    #pragma unroll
    for (int j = 0; j < 16; ++j) acc[j] = 0.0f;
    float zacc = 0.0f;
    for (int t = 0; t < CHK; ++t) {
        float kv = Kc[t * HD + d];
        zacc += kv;
        #pragma unroll
        for (int j = 0; j < 16; ++j) acc[j] += kv * Vc[t * HD + e0 + j];
    }
    float* op = KVc + ((size_t)(h * NC + c) * HD + d) * HD + e0;
    #pragma unroll
    for (int j = 0; j < 16; ++j) op[j] = acc[j];
    if ((tid & 3) == 0) Zc[(size_t)(h * NC + c) * HD + d] = zacc;
}

// exclusive prefix over chunks: load-all / scan-in-reg / store-all
__global__ __launch_bounds__(256) void attn_prefix(float* __restrict__ KVc,
                                                   float* __restrict__ Zc) {
    const int h = blockIdx.y;
    const int elem = blockIdx.x * 256 + threadIdx.x;
    size_t base = (size_t)h * NC * (HD * HD) + elem;
    float v[NC];
    #pragma unroll
    for (int c = 0; c < NC; ++c) v[c] = KVc[base + (size_t)c * (HD * HD)];
    float run = 0.0f;
    #pragma unroll
    for (int c = 0; c < NC; ++c) { float t = v[c]; v[c] = run; run += t; }
    #pragma unroll
    for (int c = 0; c < NC; ++c) KVc[base + (size_t)c * (HD * HD)] = v[c];
    if (blockIdx.x == 0 && threadIdx.x < HD) {
        size_t zb = (size_t)h * NC * HD + threadIdx.x;
        float z[NC];
        #pragma unroll
        for (int c = 0; c < NC; ++c) z[c] = Zc[zb + (size_t)c * HD];
        float zr = 0.0f;
        #pragma unroll
        for (int c = 0; c < NC; ++c) { float t = z[c]; z[c] = zr; zr += t; }
        #pragma unroll
        for (int c = 0; c < NC; ++c) Zc[zb + (size_t)c * HD] = z[c];
    }
}

__global__ __launch_bounds__(256) void attn_out(const float* __restrict__ qkv,
                                                const float* __restrict__ KVpre,
                                                const float* __restrict__ Zpre,
                                                unsigned short* __restrict__ attn) {
    const int c = blockIdx.x, h = blockIdx.y, tid = threadIdx.x;
    __shared__ float Qc[CHK * HD], KVs[CHK * HD], Pre[HD * HD], Sc[CHK * CHK];
    __shared__ float zp[HD], den[CHK];
    const int s0 = c * CHK;
    #pragma unroll
    for (int p = 0; p < 4; ++p) {
        int cc = p * 256 + tid;
        int t = cc >> 4, dp = (cc & 15) * 4;
        *(float4*)&Qc[t * HD + dp]  = *(const float4*)(qkv + (size_t)(s0 + t) * QS +     h * HD + dp);
        *(float4*)&KVs[t * HD + dp] = *(const float4*)(qkv + (size_t)(s0 + t) * QS + D + h * HD + dp);
        ((float4*)Pre)[cc] = *(const float4*)(KVpre + (size_t)(h * NC + c) * (HD * HD) + cc * 4);
    }
    if (tid < HD) zp[tid] = Zpre[(size_t)(h * NC + c) * HD + tid];
    __syncthreads();

    const int tt = tid >> 2, i0 = (tid & 3) * 16;
    for (int i = i0; i < i0 + 16; ++i) {
        float sv = 0.0f;
        for (int d2 = 0; d2 < HD; ++d2) sv += Qc[tt * HD + d2] * KVs[i * HD + d2];
        Sc[tt * CHK + i] = (i <= tt) ? sv : 0.0f;
    }
    __syncthreads();

    if (tid < CHK) {
        float dv = 1e-6f;
        for (int d2 = 0; d2 < HD; ++d2) dv += Qc[tid * HD + d2] * zp[d2];
        for (int i = 0; i < CHK; ++i) dv += Sc[tid * CHK + i];
        den[tid] = dv;
    }
    #pragma unroll
    for (int p = 0; p < 4; ++p) {
        int cc = p * 256 + tid;
        int t = cc >> 4, dp = (cc & 15) * 4;
        *(float4*)&KVs[t * HD + dp] = *(const float4*)(qkv + (size_t)(s0 + t) * QS + 2 * D + h * HD + dp);
    }
    __syncthreads();

    float o[16];
    #pragma unroll
    for (int j = 0; j < 16; ++j) o[j] = 0.0f;
    for (int d2 = 0; d2 < HD; ++d2) {
        float qv = Qc[tt * HD + d2];
        float sv = Sc[tt * CHK + d2];
        #pragma unroll
        for (int j = 0; j < 16; ++j)
            o[j] += qv * Pre[d2 * HD + i0 + j] + sv * KVs[d2 * HD + i0 + j];
    }
    const float inv = 1.0f / den[tt];
    unsigned short* op = attn + (size_t)(s0 + tt) * D + h * HD + i0;
    #pragma unroll
    for (int j0 = 0; j0 < 16; j0 += 4) {
        ushort4 ov = { f2bf(o[j0] * inv), f2bf(o[j0 + 1] * inv),
                       f2bf(o[j0 + 2] * inv), f2bf(o[j0 + 3] * inv) };
        *(ushort4*)(op + j0) = ov;
    }
}

// ---------------- launcher ----------------
extern "C" void kernel_launch(void* const* d_in, const int* in_sizes, int n_in,
                              void* d_out, int out_size, void* d_ws, size_t ws_size,
                              hipStream_t stream) {
    const float* x   = (const float*)d_in[0];
    const float* Wq  = (const float*)d_in[1];
    const float* bq  = (const float*)d_in[2];
    const float* Wk  = (const float*)d_in[3];
    const float* bk  = (const float*)d_in[4];
    const float* Wv  = (const float*)d_in[5];
    const float* bv  = (const float*)d_in[6];
    const float* Wo  = (const float*)d_in[7];
    const float* bo  = (const float*)d_in[8];
    const float* W1  = (const float*)d_in[9];
    const float* b1  = (const float*)d_in[10];
    const float* W2  = (const float*)d_in[11];
    const float* b2  = (const float*)d_in[12];
    const float* g1  = (const float*)d_in[13];
    const float* be1 = (const float*)d_in[14];
    const float* g2  = (const float*)d_in[15];
    const float* be2 = (const float*)d_in[16];
    float* out = (float*)d_out;

    char* wsp = (char*)d_ws;
    auto alloc = [&](size_t bytes) {
        char* p = wsp;
        wsp += (bytes + 255) & ~(size_t)255;
        return p;
    };
    unsigned short* h1   = (unsigned short*)alloc((size_t)S * D * 2);   // LN1 out; reused as LN2 out
    unsigned short* attn = (unsigned short*)alloc((size_t)S * D * 2);
    unsigned short* gbuf = (unsigned short*)alloc((size_t)S * FF * 2);
    float* x2   = (float*)alloc((size_t)S * D * 4);
    unsigned short* Wqkvb = (unsigned short*)alloc((size_t)3 * D * D * 2);
    unsigned short* Wob   = (unsigned short*)alloc((size_t)D * D * 2);
    unsigned short* W1b   = (unsigned short*)alloc((size_t)FF * D * 2);
    unsigned short* W2b   = (unsigned short*)alloc((size_t)D * FF * 2);
    float* KVc  = (float*)alloc((size_t)H * NC * HD * HD * 4);          // in-place prefix
    float* Zc   = (float*)alloc((size_t)H * NC * HD * 4);               // in-place prefix
    // union region: qkv (24 MB, dead after attn_out) / out-proj raw fp32 (8 MB)
    //               / FFN2 split-K partials (32 MB)
    char* uni = (char*)alloc((size_t)32 * 1024 * 1024);
    float* qkv   = (float*)uni;          // S x (3*D) fp32
    float* parts = (float*)uni;          // up to 4 x S x D fp32

    // weight cvt + LN1, one launch
    cvt_ln<<<S + CVT_BLOCKS, 256, 0, stream>>>(x, g1, be1, h1,
                                               Wq, Wk, Wv, Wo, W1, W2,
                                               Wqkvb, Wob, W1b, W2b);

    // fused QKV projection: M=2048, N=3072, K=1024 -> 192 blocks
    gemm_bt2<EPI_QKV><<<dim3(S / 256, 3 * D / 128, 1), 512, 0, stream>>>(
        h1, Wqkvb, bq, bk, bv, qkv, S, 3 * D, D, 1);

    // chunked causal linear attention
    attn_chunk_sums<<<dim3(NC, H), 256, 0, stream>>>(qkv, KVc, Zc);
    attn_prefix<<<dim3(16, H), 256, 0, stream>>>(KVc, Zc);
    attn_out<<<dim3(NC, H), 256, 0, stream>>>(qkv, KVc, Zc, attn);

    // out-proj: 128x64 tile, K=1024, no split-K -> 256 blocks, raw fp32; LN fused after
    gemm_n64<EPI_PART><<<dim3(S / 128, D / 64, 1), 256, 0, stream>>>(
        attn, Wob, nullptr, nullptr, parts, S, D, D);
    reduce_ln<1><<<S, 256, 0, stream>>>(parts, bo, x, x2, g2, be2, h1);

    // FFN1: M=2048, N=4096, K=1024 -> 256 blocks, GELU fused, bf16 out
    gemm_bt2<EPI_GELU_BF16><<<dim3(S / 256, FF / 128, 1), 512, 0, stream>>>(
        h1, W1b, b1, nullptr, nullptr, gbuf, S, FF, D, 1);

    // FFN2: 256x128 split-K=4 -> 256 blocks; reduce adds bias + residual(x2) -> out
    gemm_bt2<EPI_PART><<<dim3(S / 256, D / 128, 4), 512, 0, stream>>>(
        gbuf, W2b, nullptr, nullptr, nullptr, parts, S, D, FF, 4);
    reduce_bias_res<4><<<(S * D / 4 + 255) / 256, 256, 0, stream>>>(
        parts, b2, x2, out, D / 4, S * D / 4);
}

// Round 9
// 287.732 us; speedup vs baseline: 2.0098x; 1.0203x over previous
//
#include <hip/hip_runtime.h>
#include <hip/hip_bf16.h>
#include <math.h>

// Problem constants (B=1)
constexpr int S  = 2048;
constexpr int D  = 1024;
constexpr int H  = 16;
constexpr int HD = 64;
constexpr int FF = 4096;
constexpr int NC  = 32;   // number of chunks for linear attention
constexpr int CHK = 64;   // chunk length (timesteps)
constexpr int QS  = 3 * D; // fused qkv row stride

typedef __attribute__((ext_vector_type(8))) short bf16x8;
typedef __attribute__((ext_vector_type(16))) float f32x16;

__device__ inline unsigned short f2bf(float f) {
    unsigned int u = __float_as_uint(f);
    u = (u + 0x7FFFu + ((u >> 16) & 1u)) >> 16;   // RNE
    return (unsigned short)u;
}

// ---------------- fused weight-convert (fp32->bf16) + LayerNorm1, ONE launch ----------------
constexpr int DD4 = D * D / 4;       // 262144
constexpr int FD4 = FF * D / 4;      // 1048576
constexpr int CVT_TOTAL4 = 4 * DD4 + 2 * FD4;   // 3145728
constexpr int CVT_BLOCKS = CVT_TOTAL4 / 256;    // 12288

// blocks [0, S): LayerNorm of row blockIdx.x; blocks [S, S+CVT_BLOCKS): weight cvt
__global__ __launch_bounds__(256) void cvt_ln(const float* __restrict__ x,
                                              const float* __restrict__ g,
                                              const float* __restrict__ b,
                                              unsigned short* __restrict__ lnout,
                                              const float* __restrict__ Wq,
                                              const float* __restrict__ Wk,
                                              const float* __restrict__ Wv,
                                              const float* __restrict__ Wo,
                                              const float* __restrict__ W1,
                                              const float* __restrict__ W2,
                                              unsigned short* __restrict__ Wqkvb,
                                              unsigned short* __restrict__ Wob,
                                              unsigned short* __restrict__ W1b,
                                              unsigned short* __restrict__ W2b) {
    const int tid = threadIdx.x;
    if (blockIdx.x >= S) {
        int i = (blockIdx.x - S) * 256 + tid;
        const float* s;
        unsigned short* dp;
        if (i < DD4)                 { s = Wq + (size_t)i * 4;               dp = Wqkvb + (size_t)i * 4; }
        else if (i < 2 * DD4)        { s = Wk + (size_t)(i - DD4) * 4;       dp = Wqkvb + (size_t)i * 4; }
        else if (i < 3 * DD4)        { s = Wv + (size_t)(i - 2 * DD4) * 4;   dp = Wqkvb + (size_t)i * 4; }
        else if (i < 4 * DD4)        { s = Wo + (size_t)(i - 3 * DD4) * 4;   dp = Wob + (size_t)(i - 3 * DD4) * 4; }
        else if (i < 4 * DD4 + FD4)  { s = W1 + (size_t)(i - 4 * DD4) * 4;   dp = W1b + (size_t)(i - 4 * DD4) * 4; }
        else                         { s = W2 + (size_t)(i - 4 * DD4 - FD4) * 4; dp = W2b + (size_t)(i - 4 * DD4 - FD4) * 4; }
        float4 v = *(const float4*)s;
        ushort4 o = { f2bf(v.x), f2bf(v.y), f2bf(v.z), f2bf(v.w) };
        *(ushort4*)dp = o;
        return;
    }
    const int row = blockIdx.x;
    float4 v = ((const float4*)(x + (size_t)row * D))[tid];
    float s  = v.x + v.y + v.z + v.w;
    float ss = v.x*v.x + v.y*v.y + v.z*v.z + v.w*v.w;
    #pragma unroll
    for (int off = 32; off > 0; off >>= 1) {
        s  += __shfl_down(s, off);
        ss += __shfl_down(ss, off);
    }
    __shared__ float sw[4], ssw[4];
    if ((tid & 63) == 0) { sw[tid >> 6] = s; ssw[tid >> 6] = ss; }
    __syncthreads();
    s  = sw[0] + sw[1] + sw[2] + sw[3];
    ss = ssw[0] + ssw[1] + ssw[2] + ssw[3];
    const float mu = s * (1.0f / D);
    const float rs = rsqrtf(ss * (1.0f / D) - mu * mu + 1e-5f);
    float4 gv = ((const float4*)g)[tid];
    float4 bv = ((const float4*)b)[tid];
    ushort4 o = { f2bf((v.x - mu) * rs * gv.x + bv.x),
                  f2bf((v.y - mu) * rs * gv.y + bv.y),
                  f2bf((v.z - mu) * rs * gv.z + bv.z),
                  f2bf((v.w - mu) * rs * gv.w + bv.w) };
    ((ushort4*)(lnout + (size_t)row * D))[tid] = o;
}

// ---------------- reduce (KS copies) + bias + residual + LayerNorm ----------------
template <int KS>
__global__ __launch_bounds__(256) void reduce_ln(const float* __restrict__ part,
                                                 const float* __restrict__ bias,
                                                 const float* __restrict__ res,
                                                 float* __restrict__ x2,
                                                 const float* __restrict__ g,
                                                 const float* __restrict__ b,
                                                 unsigned short* __restrict__ out) {
    const int row = blockIdx.x, tid = threadIdx.x;
    const size_t i4 = (size_t)row * 256 + tid;       // float4 index into SxD
    float4 a = ((const float4*)part)[i4];
    #pragma unroll
    for (int z = 1; z < KS; ++z) {
        float4 p = ((const float4*)part)[(size_t)z * S * 256 + i4];
        a.x += p.x; a.y += p.y; a.z += p.z; a.w += p.w;
    }
    float4 bi = ((const float4*)bias)[tid];
    float4 r  = ((const float4*)res)[i4];
    a.x += bi.x + r.x; a.y += bi.y + r.y; a.z += bi.z + r.z; a.w += bi.w + r.w;
    ((float4*)x2)[i4] = a;
    float s  = a.x + a.y + a.z + a.w;
    float ss = a.x*a.x + a.y*a.y + a.z*a.z + a.w*a.w;
    #pragma unroll
    for (int off = 32; off > 0; off >>= 1) {
        s  += __shfl_down(s, off);
        ss += __shfl_down(ss, off);
    }
    __shared__ float sw[4], ssw[4];
    if ((tid & 63) == 0) { sw[tid >> 6] = s; ssw[tid >> 6] = ss; }
    __syncthreads();
    s  = sw[0] + sw[1] + sw[2] + sw[3];
    ss = ssw[0] + ssw[1] + ssw[2] + ssw[3];
    const float mu = s * (1.0f / D);
    const float rs = rsqrtf(ss * (1.0f / D) - mu * mu + 1e-5f);
    float4 gv = ((const float4*)g)[tid];
    float4 bv = ((const float4*)b)[tid];
    ushort4 o = { f2bf((a.x - mu) * rs * gv.x + bv.x),
                  f2bf((a.y - mu) * rs * gv.y + bv.y),
                  f2bf((a.z - mu) * rs * gv.z + bv.z),
                  f2bf((a.w - mu) * rs * gv.w + bv.w) };
    ((ushort4*)(out + (size_t)row * D))[tid] = o;
}

// ---------------- split-K reduce (final output, no LN) ----------------
template <int KS>
__global__ __launch_bounds__(256) void reduce_bias_res(const float* __restrict__ part,
                                                       const float* __restrict__ bias,
                                                       const float* __restrict__ res,
                                                       float* __restrict__ out,
                                                       int N4, int total4) {
    int i = blockIdx.x * 256 + threadIdx.x;
    if (i >= total4) return;
    float4 a = ((const float4*)part)[i];
    #pragma unroll
    for (int z = 1; z < KS; ++z) {
        float4 p = ((const float4*)part)[(size_t)z * total4 + i];
        a.x += p.x; a.y += p.y; a.z += p.z; a.w += p.w;
    }
    float4 b = ((const float4*)bias)[i % N4];
    float4 r = ((const float4*)res)[i];
    a.x += b.x + r.x; a.y += b.y + r.y; a.z += b.z + r.z; a.w += b.w + r.w;
    ((float4*)out)[i] = a;
}

// Epilogue variants
enum { EPI_F32 = 0, EPI_QKV = 1, EPI_GELU_BF16 = 2, EPI_PART = 3, EPI_BIAS_RES = 4 };

// ---------------- bf16 MFMA GEMM, 256x128 tile (QKV / FFN1 / FFN2 split-K) ----------------
// EXACT R5 inner loop (best measured: 291.27 us total). BK=64, 512 threads
// (8 waves 4Mx2N), v_mfma_f32_32x32x16_bf16, DEPTH-3 LDS pipeline (144 KB,
// 1 block/CU), COUNTED vmcnt(6) (T3+T4, m218): at iter t only tile t+1's 6
// loads are newer, so vmcnt(6) proves tile t landed; raw s_barrier; lgkmcnt(0)
// folded in. R8's 4-phase cadence was NULL (293.6 vs 291.3) -> reverted.
// XOR-swizzled LDS (measured SQ_LDS_BANK_CONFLICT == 0): slot p of row r holds
// global chunk p ^ ((r>>1)&7); XOR applied to GLOBAL source index.
// C/D 32x32 layout [m74/m101]: col = lane&31, row = (reg&3)+8*(reg>>2)+4*(lane>>5).
template <int EPI>
__global__ __launch_bounds__(512, 2) void gemm_bt2(const unsigned short* __restrict__ A,
                                                   const unsigned short* __restrict__ W,
                                                   const float* __restrict__ bias,
                                                   const float* __restrict__ bias2,
                                                   const float* __restrict__ bias3,
                                                   void* __restrict__ outp,
                                                   int M, int N, int K, int kSplit) {
    __shared__ unsigned short As[3][256 * 64];   // 96 KB
    __shared__ unsigned short Bs[3][128 * 64];   // 48 KB
    const int tid   = threadIdx.x;
    const int tileM = blockIdx.x * 256;
    const int tileN = blockIdx.y * 128;
    const int w    = tid >> 6, lane = tid & 63;
    const int wm   = (w >> 1) * 64, wn = (w & 1) * 64;
    const int l31  = lane & 31, lhi = lane >> 5;
    const int sw32 = (l31 >> 1) & 7;
    const int kLen   = K / kSplit;
    const int kStart = blockIdx.z * kLen;
    const int nt     = kLen >> 6;

    f32x16 acc[2][2];
    #pragma unroll
    for (int i = 0; i < 2; ++i)
        #pragma unroll
        for (int j = 0; j < 2; ++j) acc[i][j] = (f32x16)(0.0f);

    auto stage = [&](int buf, int k0) {
        #pragma unroll
        for (int p = 0; p < 4; ++p) {                  // A: 2048 16B chunks
            const int c   = p * 512 + tid;
            const int row = c >> 3;
            const int kc  = (c & 7) ^ ((row >> 1) & 7);
            __builtin_amdgcn_global_load_lds(
                (const __attribute__((address_space(1))) unsigned int*)
                    (A + (size_t)(tileM + row) * K + k0 + kc * 8),
                (__attribute__((address_space(3))) unsigned int*)&As[buf][c * 8],
                16, 0, 0);
        }
        #pragma unroll
        for (int p = 0; p < 2; ++p) {                  // B: 1024 16B chunks
            const int c   = p * 512 + tid;
            const int row = c >> 3;
            const int kc  = (c & 7) ^ ((row >> 1) & 7);
            __builtin_amdgcn_global_load_lds(
                (const __attribute__((address_space(1))) unsigned int*)
                    (W + (size_t)(tileN + row) * K + k0 + kc * 8),
                (__attribute__((address_space(3))) unsigned int*)&Bs[buf][c * 8],
                16, 0, 0);
        }
    };

    stage(0, kStart);
    if (nt > 1) stage(1, kStart + 64);

    int k0 = kStart;
    for (int t = 0; t < nt; ++t, k0 += 64) {
        if (t + 1 < nt) asm volatile("s_waitcnt vmcnt(6) lgkmcnt(0)" ::: "memory");
        else            asm volatile("s_waitcnt vmcnt(0) lgkmcnt(0)" ::: "memory");
        __builtin_amdgcn_s_barrier();
        if (t + 2 < nt) stage((t + 2) % 3, k0 + 128);

        const unsigned short* Ab = &As[t % 3][0];
        const unsigned short* Bb = &Bs[t % 3][0];
        bf16x8 af[4][2], bfv[4][2];
        #pragma unroll
        for (int s = 0; s < 4; ++s) {
            const int slot = (2 * s + lhi) ^ sw32;
            #pragma unroll
            for (int i = 0; i < 2; ++i)
                af[s][i] = *(const bf16x8*)&Ab[(wm + i * 32 + l31) * 64 + slot * 8];
            #pragma unroll
            for (int j = 0; j < 2; ++j)
                bfv[s][j] = *(const bf16x8*)&Bb[(wn + j * 32 + l31) * 64 + slot * 8];
        }
        __builtin_amdgcn_s_setprio(1);
        #pragma unroll
        for (int s = 0; s < 4; ++s)
            #pragma unroll
            for (int i = 0; i < 2; ++i)
                #pragma unroll
                for (int j = 0; j < 2; ++j)
                    acc[i][j] = __builtin_amdgcn_mfma_f32_32x32x16_bf16(af[s][i], bfv[s][j], acc[i][j], 0, 0, 0);
        __builtin_amdgcn_s_setprio(0);
    }

    #pragma unroll
    for (int i = 0; i < 2; ++i) {
        #pragma unroll
        for (int j = 0; j < 2; ++j) {
            const int col = tileN + wn + j * 32 + l31;
            #pragma unroll
            for (int q = 0; q < 4; ++q) {
                const int rbase = tileM + wm + i * 32 + q * 8 + lhi * 4;
                #pragma unroll
                for (int r = 0; r < 4; ++r) {
                    const int row = rbase + r;
                    const size_t off = (size_t)row * N + col;
                    float v = acc[i][j][q * 4 + r];
                    if constexpr (EPI == EPI_PART) {
                        ((float*)outp)[(size_t)blockIdx.z * (size_t)M * (size_t)N + off] = v;
                    } else if constexpr (EPI == EPI_QKV) {
                        float bc = (col < D) ? bias[col] : ((col < 2 * D) ? bias2[col - D] : bias3[col - 2 * D]);
                        v += bc;
                        if (col < 2 * D) v = v > 0.0f ? v + 1.0f : __expf(v);
                        ((float*)outp)[off] = v;
                    } else if constexpr (EPI == EPI_GELU_BF16) {
                        v += bias[col];
                        float gl = 0.5f * v * (1.0f + erff(v * 0.70710678118654752f));
                        ((unsigned short*)outp)[off] = f2bf(gl);
                    } else {
                        v += bias[col];
                        ((float*)outp)[off] = v;
                    }
                }
            }
        }
    }
}

// ---------------- bf16 MFMA GEMM, 128x64 tile (out-proj only, K=1024) ----------------
// 256 threads (4 waves 2Mx2N), depth-3 counted-vmcnt schedule, same swizzle.
// LDS 72 KB -> 2 blocks/CU; grid 16x16=256. Kept ONLY for K=1024 out-proj
// (R4: at K=4096 it measured 60 us vs <40.6 for 256x128 split-K).
template <int EPI>
__global__ __launch_bounds__(256, 2) void gemm_n64(const unsigned short* __restrict__ A,
                                                   const unsigned short* __restrict__ W,
                                                   const float* __restrict__ bias,
                                                   const float* __restrict__ res,
                                                   void* __restrict__ outp,
                                                   int M, int N, int K) {
    __shared__ unsigned short As[3][128 * 64];   // 48 KB
    __shared__ unsigned short Bs[3][64 * 64];    // 24 KB
    const int tid   = threadIdx.x;
    const int tileM = blockIdx.x * 128;
    const int tileN = blockIdx.y * 64;
    const int w    = tid >> 6, lane = tid & 63;
    const int wm   = (w >> 1) * 64, wn = (w & 1) * 32;
    const int l31  = lane & 31, lhi = lane >> 5;
    const int sw32 = (l31 >> 1) & 7;
    const int nt   = K >> 6;

    f32x16 acc[2];
    #pragma unroll
    for (int i = 0; i < 2; ++i) acc[i] = (f32x16)(0.0f);

    auto stage = [&](int buf, int k0) {
        #pragma unroll
        for (int p = 0; p < 4; ++p) {                  // A: 128x64 = 1024 16B chunks
            const int c   = p * 256 + tid;
            const int row = c >> 3;
            const int kc  = (c & 7) ^ ((row >> 1) & 7);
            __builtin_amdgcn_global_load_lds(
                (const __attribute__((address_space(1))) unsigned int*)
                    (A + (size_t)(tileM + row) * K + k0 + kc * 8),
                (__attribute__((address_space(3))) unsigned int*)&As[buf][c * 8],
                16, 0, 0);
        }
        #pragma unroll
        for (int p = 0; p < 2; ++p) {                  // B: 64x64 = 512 16B chunks
            const int c   = p * 256 + tid;
            const int row = c >> 3;
            const int kc  = (c & 7) ^ ((row >> 1) & 7);
            __builtin_amdgcn_global_load_lds(
                (const __attribute__((address_space(1))) unsigned int*)
                    (W + (size_t)(tileN + row) * K + k0 + kc * 8),
                (__attribute__((address_space(3))) unsigned int*)&Bs[buf][c * 8],
                16, 0, 0);
        }
    };

    stage(0, 0);
    if (nt > 1) stage(1, 64);

    int k0 = 0;
    for (int t = 0; t < nt; ++t, k0 += 64) {
        if (t + 1 < nt) asm volatile("s_waitcnt vmcnt(6) lgkmcnt(0)" ::: "memory");
        else            asm volatile("s_waitcnt vmcnt(0) lgkmcnt(0)" ::: "memory");
        __builtin_amdgcn_s_barrier();
        if (t + 2 < nt) stage((t + 2) % 3, k0 + 128);

        const unsigned short* Ab = &As[t % 3][0];
        const unsigned short* Bb = &Bs[t % 3][0];
        bf16x8 af[4][2], bfv[4];
        #pragma unroll
        for (int s = 0; s < 4; ++s) {
            const int slot = (2 * s + lhi) ^ sw32;
            #pragma unroll
            for (int i = 0; i < 2; ++i)
                af[s][i] = *(const bf16x8*)&Ab[(wm + i * 32 + l31) * 64 + slot * 8];
            bfv[s] = *(const bf16x8*)&Bb[(wn + l31) * 64 + slot * 8];
        }
        __builtin_amdgcn_s_setprio(1);
        #pragma unroll
        for (int s = 0; s < 4; ++s)
            #pragma unroll
            for (int i = 0; i < 2; ++i)
                acc[i] = __builtin_amdgcn_mfma_f32_32x32x16_bf16(af[s][i], bfv[s], acc[i], 0, 0, 0);
        __builtin_amdgcn_s_setprio(0);
    }

    #pragma unroll
    for (int i = 0; i < 2; ++i) {
        const int col = tileN + wn + l31;
        #pragma unroll
        for (int q = 0; q < 4; ++q) {
            const int rbase = tileM + wm + i * 32 + q * 8 + lhi * 4;
            #pragma unroll
            for (int r = 0; r < 4; ++r) {
                const int row = rbase + r;
                const size_t off = (size_t)row * N + col;
                float v = acc[i][q * 4 + r];
                if constexpr (EPI == EPI_BIAS_RES) {
                    v += bias[col] + res[off];
                    ((float*)outp)[off] = v;
                } else {                                // EPI_PART: raw fp32
                    ((float*)outp)[off] = v;
                }
            }
        }
    }
}

// ---------------- linear attention, chunked causal scan (fp32) ----------------
__global__ __launch_bounds__(256) void attn_chunk_sums(const float* __restrict__ qkv,
                                                       float* __restrict__ KVc,
                                                       float* __restrict__ Zc) {
    const int c = blockIdx.x, h = blockIdx.y, tid = threadIdx.x;
    __shared__ float Kc[CHK * HD], Vc[CHK * HD];
    const int s0 = c * CHK;
    #pragma unroll
    for (int p = 0; p < 4; ++p) {
        int cc = p * 256 + tid;
        int t = cc >> 4, dp = (cc & 15) * 4;
        *(float4*)&Kc[t * HD + dp] = *(const float4*)(qkv + (size_t)(s0 + t) * QS + D     + h * HD + dp);
        *(float4*)&Vc[t * HD + dp] = *(const float4*)(qkv + (size_t)(s0 + t) * QS + 2 * D + h * HD + dp);
    }
    __syncthreads();
    const int d = tid >> 2, e0 = (tid & 3) * 16;
    float acc[16];
    #pragma unroll
    for (int j = 0; j < 16; ++j) acc[j] = 0.0f;
    float zacc = 0.0f;
    for (int t = 0; t < CHK; ++t) {
        float kv = Kc[t * HD + d];
        zacc += kv;
        #pragma unroll
        for (int j = 0; j < 16; ++j) acc[j] += kv * Vc[t * HD + e0 + j];
    }
    float* op = KVc + ((size_t)(h * NC + c) * HD + d) * HD + e0;
    #pragma unroll
    for (int j = 0; j < 16; ++j) op[j] = acc[j];
    if ((tid & 3) == 0) Zc[(size_t)(h * NC + c) * HD + d] = zacc;
}

// exclusive prefix over chunks: load-all / scan-in-reg / store-all
__global__ __launch_bounds__(256) void attn_prefix(float* __restrict__ KVc,
                                                   float* __restrict__ Zc) {
    const int h = blockIdx.y;
    const int elem = blockIdx.x * 256 + threadIdx.x;
    size_t base = (size_t)h * NC * (HD * HD) + elem;
    float v[NC];
    #pragma unroll
    for (int c = 0; c < NC; ++c) v[c] = KVc[base + (size_t)c * (HD * HD)];
    float run = 0.0f;
    #pragma unroll
    for (int c = 0; c < NC; ++c) { float t = v[c]; v[c] = run; run += t; }
    #pragma unroll
    for (int c = 0; c < NC; ++c) KVc[base + (size_t)c * (HD * HD)] = v[c];
    if (blockIdx.x == 0 && threadIdx.x < HD) {
        size_t zb = (size_t)h * NC * HD + threadIdx.x;
        float z[NC];
        #pragma unroll
        for (int c = 0; c < NC; ++c) z[c] = Zc[zb + (size_t)c * HD];
        float zr = 0.0f;
        #pragma unroll
        for (int c = 0; c < NC; ++c) { float t = z[c]; z[c] = zr; zr += t; }
        #pragma unroll
        for (int c = 0; c < NC; ++c) Zc[zb + (size_t)c * HD] = z[c];
    }
}

// attn_out with STRIDE-68 LDS padding (from R7's verified P4): unpadded [64][64]
// fp32 rows made the den pass a 32-way bank conflict (all lanes read col d2 at
// 256B stride) and QK^T 16-way. Pad rows to 68 floats -> worst case 8-way.
__global__ __launch_bounds__(256) void attn_out(const float* __restrict__ qkv,
                                                const float* __restrict__ KVpre,
                                                const float* __restrict__ Zpre,
                                                unsigned short* __restrict__ attn) {
    const int c = blockIdx.x, h = blockIdx.y, tid = threadIdx.x;
    __shared__ float Qc[CHK * 68], KVs[CHK * 68], Sc[CHK * 68];
    __shared__ float Pre[HD * HD], zp[HD], den[CHK];
    const int s0 = c * CHK;
    #pragma unroll
    for (int p = 0; p < 4; ++p) {
        int cc = p * 256 + tid;
        int t = cc >> 4, dp = (cc & 15) * 4;
        *(float4*)&Qc[t * 68 + dp]  = *(const float4*)(qkv + (size_t)(s0 + t) * QS +     h * HD + dp);
        *(float4*)&KVs[t * 68 + dp] = *(const float4*)(qkv + (size_t)(s0 + t) * QS + D + h * HD + dp);
        ((float4*)Pre)[cc] = *(const float4*)(KVpre + (size_t)(h * NC + c) * (HD * HD) + cc * 4);
    }
    if (tid < HD) zp[tid] = Zpre[(size_t)(h * NC + c) * HD + tid];
    __syncthreads();

    const int tt = tid >> 2, i0 = (tid & 3) * 16;
    for (int i = i0; i < i0 + 16; ++i) {
        float sv = 0.0f;
        for (int d2 = 0; d2 < HD; ++d2) sv += Qc[tt * 68 + d2] * KVs[i * 68 + d2];
        Sc[tt * 68 + i] = (i <= tt) ? sv : 0.0f;
    }
    __syncthreads();

    if (tid < CHK) {
        float dv = 1e-6f;
        for (int d2 = 0; d2 < HD; ++d2) dv += Qc[tid * 68 + d2] * zp[d2];
        for (int i = 0; i < CHK; ++i) dv += Sc[tid * 68 + i];
        den[tid] = dv;
    }
    #pragma unroll
    for (int p = 0; p < 4; ++p) {
        int cc = p * 256 + tid;
        int t = cc >> 4, dp = (cc & 15) * 4;
        *(float4*)&KVs[t * 68 + dp] = *(const float4*)(qkv + (size_t)(s0 + t) * QS + 2 * D + h * HD + dp);
    }
    __syncthreads();

    float o[16];
    #pragma unroll
    for (int j = 0; j < 16; ++j) o[j] = 0.0f;
    for (int d2 = 0; d2 < HD; ++d2) {
        float qv = Qc[tt * 68 + d2];
        float sv = Sc[tt * 68 + d2];
        #pragma unroll
        for (int j = 0; j < 16; ++j)
            o[j] += qv * Pre[d2 * HD + i0 + j] + sv * KVs[d2 * 68 + i0 + j];
    }
    const float inv = 1.0f / den[tt];
    unsigned short* op = attn + (size_t)(s0 + tt) * D + h * HD + i0;
    #pragma unroll
    for (int j0 = 0; j0 < 16; j0 += 4) {
        ushort4 ov = { f2bf(o[j0] * inv), f2bf(o[j0 + 1] * inv),
                       f2bf(o[j0 + 2] * inv), f2bf(o[j0 + 3] * inv) };
        *(ushort4*)(op + j0) = ov;
    }
}

// ---------------- launcher ----------------
extern "C" void kernel_launch(void* const* d_in, const int* in_sizes, int n_in,
                              void* d_out, int out_size, void* d_ws, size_t ws_size,
                              hipStream_t stream) {
    const float* x   = (const float*)d_in[0];
    const float* Wq  = (const float*)d_in[1];
    const float* bq  = (const float*)d_in[2];
    const float* Wk  = (const float*)d_in[3];
    const float* bk  = (const float*)d_in[4];
    const float* Wv  = (const float*)d_in[5];
    const float* bv  = (const float*)d_in[6];
    const float* Wo  = (const float*)d_in[7];
    const float* bo  = (const float*)d_in[8];
    const float* W1  = (const float*)d_in[9];
    const float* b1  = (const float*)d_in[10];
    const float* W2  = (const float*)d_in[11];
    const float* b2  = (const float*)d_in[12];
    const float* g1  = (const float*)d_in[13];
    const float* be1 = (const float*)d_in[14];
    const float* g2  = (const float*)d_in[15];
    const float* be2 = (const float*)d_in[16];
    float* out = (float*)d_out;

    char* wsp = (char*)d_ws;
    auto alloc = [&](size_t bytes) {
        char* p = wsp;
        wsp += (bytes + 255) & ~(size_t)255;
        return p;
    };
    unsigned short* h1   = (unsigned short*)alloc((size_t)S * D * 2);   // LN1 out; reused as LN2 out
    unsigned short* attn = (unsigned short*)alloc((size_t)S * D * 2);
    unsigned short* gbuf = (unsigned short*)alloc((size_t)S * FF * 2);
    float* x2   = (float*)alloc((size_t)S * D * 4);
    unsigned short* Wqkvb = (unsigned short*)alloc((size_t)3 * D * D * 2);
    unsigned short* Wob   = (unsigned short*)alloc((size_t)D * D * 2);
    unsigned short* W1b   = (unsigned short*)alloc((size_t)FF * D * 2);
    unsigned short* W2b   = (unsigned short*)alloc((size_t)D * FF * 2);
    float* KVc  = (float*)alloc((size_t)H * NC * HD * HD * 4);          // in-place prefix
    float* Zc   = (float*)alloc((size_t)H * NC * HD * 4);               // in-place prefix
    // union region: qkv (24 MB, dead after attn_out) / out-proj raw fp32 (8 MB)
    //               / FFN2 split-K partials (32 MB)
    char* uni = (char*)alloc((size_t)32 * 1024 * 1024);
    float* qkv   = (float*)uni;          // S x (3*D) fp32
    float* parts = (float*)uni;          // up to 4 x S x D fp32

    // weight cvt + LN1, one launch
    cvt_ln<<<S + CVT_BLOCKS, 256, 0, stream>>>(x, g1, be1, h1,
                                               Wq, Wk, Wv, Wo, W1, W2,
                                               Wqkvb, Wob, W1b, W2b);

    // fused QKV projection: M=2048, N=3072, K=1024 -> 192 blocks
    gemm_bt2<EPI_QKV><<<dim3(S / 256, 3 * D / 128, 1), 512, 0, stream>>>(
        h1, Wqkvb, bq, bk, bv, qkv, S, 3 * D, D, 1);

    // chunked causal linear attention
    attn_chunk_sums<<<dim3(NC, H), 256, 0, stream>>>(qkv, KVc, Zc);
    attn_prefix<<<dim3(16, H), 256, 0, stream>>>(KVc, Zc);
    attn_out<<<dim3(NC, H), 256, 0, stream>>>(qkv, KVc, Zc, attn);

    // out-proj: 128x64 tile, K=1024, no split-K -> 256 blocks, raw fp32; LN fused after
    gemm_n64<EPI_PART><<<dim3(S / 128, D / 64, 1), 256, 0, stream>>>(
        attn, Wob, nullptr, nullptr, parts, S, D, D);
    reduce_ln<1><<<S, 256, 0, stream>>>(parts, bo, x, x2, g2, be2, h1);

    // FFN1: M=2048, N=4096, K=1024 -> 256 blocks, GELU fused, bf16 out
    gemm_bt2<EPI_GELU_BF16><<<dim3(S / 256, FF / 128, 1), 512, 0, stream>>>(
        h1, W1b, b1, nullptr, nullptr, gbuf, S, FF, D, 1);

    // FFN2: 256x128 split-K=4 -> 256 blocks; reduce adds bias + residual(x2) -> out
    gemm_bt2<EPI_PART><<<dim3(S / 256, D / 128, 4), 512, 0, stream>>>(
        gbuf, W2b, nullptr, nullptr, nullptr, parts, S, D, FF, 4);
    reduce_bias_res<4><<<(S * D / 4 + 255) / 256, 256, 0, stream>>>(
        parts, b2, x2, out, D / 4, S * D / 4);
}